// Round 1
// baseline (344.542 us; speedup 1.0000x reference)
//
#include <hip/hip_runtime.h>
#include <math.h>

// Problem constants
#define BB 512
#define TT 2048
#define AA 16
#define NTOT (512LL * 2048LL * 16LL)   // 16,777,216
#define GAMMA 0.99f
#define GLAM  0.9405f                  // gamma * lam, matches python double->f32
#define ENTC  1.4189385332046727f      // 0.5 + 0.5*log(2*pi)

#define NB2 2048                       // blocks for obj reduction kernel

// ---------------------------------------------------------------------------
// K1: GAE via parallel affine scan. One block (256 threads) per batch row.
// Reversed recurrence y_u = a_u * y_{u-1} + b_u with u = T-1-t:
//   u==0: (a,b)=(0,0)  -> adv[T-1]=0
//   u>=1: t=T-1-u, b=td[t]=r[t]+g*V[t+1]-V[t], a=g*lam*(1-done[t+1])
// Each thread handles 8 consecutive u; block-wide exclusive scan of affine
// composites via wave shuffles + LDS.
// ---------------------------------------------------------------------------
__global__ __launch_bounds__(256) void gae_kernel(
    const float* __restrict__ rewards, const float* __restrict__ vout,
    const int* __restrict__ dones, float* __restrict__ adv)
{
    const int b   = blockIdx.x;
    const int tid = threadIdx.x;
    const float* rw = rewards + (size_t)b * TT;
    const float* V  = vout    + (size_t)b * (TT + 1);
    const int*   dn = dones   + (size_t)b * TT;
    float*       av = adv     + (size_t)b * TT;

    float ak[8], bk[8];
    float SA = 1.f, SB = 0.f;   // segment composite (applied earliest-first)
    #pragma unroll
    for (int k = 0; k < 8; ++k) {
        int u = tid * 8 + k;
        float au, bu;
        if (u == 0) { au = 0.f; bu = 0.f; }
        else {
            int t = TT - 1 - u;                       // t in [0, T-2]
            bu = rw[t] + GAMMA * V[t + 1] - V[t];
            au = GLAM * (1.f - (float)dn[t + 1]);
        }
        ak[k] = au; bk[k] = bu;
        SB = au * SB + bu;    // compose f_u after current composite
        SA = au * SA;
    }

    const int lane = tid & 63;
    const int wave = tid >> 6;

    // wave-inclusive scan of composites; compose(me, prev): B=A_me*B_prev+B_me
    #pragma unroll
    for (int off = 1; off < 64; off <<= 1) {
        float pA = __shfl_up(SA, off, 64);
        float pB = __shfl_up(SB, off, 64);
        if (lane >= off) { SB = SA * pB + SB; SA = SA * pA; }
    }

    __shared__ float wA[4], wB[4];
    if (lane == 63) { wA[wave] = SA; wB[wave] = SB; }
    __syncthreads();

    // composite of all waves before mine (identity for wave 0)
    float PA = 1.f, PB = 0.f;
    for (int w = 0; w < wave; ++w) {
        float aw = wA[w], bw = wB[w];
        PB = aw * PB + bw;
        PA = aw * PA;
    }

    // exclusive within wave
    float EA = __shfl_up(SA, 1, 64);
    float EB = __shfl_up(SB, 1, 64);
    if (lane == 0) { EA = 1.f; EB = 0.f; }

    // carry into my segment = (E ∘ P)(0) = EA*PB + EB
    float x = EA * PB + EB;
    #pragma unroll
    for (int k = 0; k < 8; ++k) {
        x = ak[k] * x + bk[k];
        int u = tid * 8 + k;
        av[TT - 1 - u] = x;
    }
}

// ---------------------------------------------------------------------------
// K2: PPO objective partial sums. clipped == 0.8 (faithful clip bug).
// obj = min(adv*ratio, adv*0.8), ratio = (os/s)*exp(0.5*(zo^2 - z^2)).
// Grid-stride, float4 loads, f64 block partials (no atomics).
// ---------------------------------------------------------------------------
__device__ __forceinline__ float obj1(float x, float m, float s,
                                      float om, float os, float ad)
{
    float rs  = __builtin_amdgcn_rcpf(s);
    float ros = __builtin_amdgcn_rcpf(os);
    float z   = (x - m) * rs;
    float zo  = (x - om) * ros;
    float d   = 0.5f * (zo * zo - z * z);
    float ratio = os * rs * __expf(d);
    return fminf(ad * ratio, ad * 0.8f);
}

__global__ __launch_bounds__(256) void obj_kernel(
    const float* __restrict__ mu, const float* __restrict__ sigma,
    const float* __restrict__ old_mu, const float* __restrict__ old_sigma,
    const float* __restrict__ actions, const float* __restrict__ adv,
    double* __restrict__ partials)
{
    const int tid = threadIdx.x;
    const size_t gthread = (size_t)blockIdx.x * 256 + tid;
    const size_t stride  = (size_t)NB2 * 256;   // float4 stride

    const float4* m4  = (const float4*)mu;
    const float4* s4  = (const float4*)sigma;
    const float4* om4 = (const float4*)old_mu;
    const float4* os4 = (const float4*)old_sigma;
    const float4* x4  = (const float4*)actions;

    double lsum = 0.0;
    #pragma unroll 2
    for (int it = 0; it < 8; ++it) {
        size_t v = gthread + (size_t)it * stride;      // float4 index
        float4 m  = m4[v];
        float4 s  = s4[v];
        float4 om = om4[v];
        float4 os = os4[v];
        float4 x  = x4[v];
        float ad  = adv[v >> 2];                       // 4*v/16

        float o0 = obj1(x.x, m.x, s.x, om.x, os.x, ad);
        float o1 = obj1(x.y, m.y, s.y, om.y, os.y, ad);
        float o2 = obj1(x.z, m.z, s.z, om.z, os.z, ad);
        float o3 = obj1(x.w, m.w, s.w, om.w, os.w, ad);
        lsum += (double)o0 + (double)o1 + (double)o2 + (double)o3;
    }

    // wave reduce
    #pragma unroll
    for (int off = 32; off > 0; off >>= 1)
        lsum += __shfl_down(lsum, off, 64);

    __shared__ double wsum[4];
    const int lane = tid & 63, wave = tid >> 6;
    if (lane == 0) wsum[wave] = lsum;
    __syncthreads();
    if (tid == 0)
        partials[blockIdx.x] = wsum[0] + wsum[1] + wsum[2] + wsum[3];
}

// ---------------------------------------------------------------------------
// K2b: reduce 2048 partials -> mean (single block)
// ---------------------------------------------------------------------------
__global__ __launch_bounds__(256) void reduce_kernel(
    const double* __restrict__ partials, float* __restrict__ meanOut)
{
    const int tid = threadIdx.x;
    double s = 0.0;
    for (int i = tid; i < NB2; i += 256) s += partials[i];
    #pragma unroll
    for (int off = 32; off > 0; off >>= 1)
        s += __shfl_down(s, off, 64);
    __shared__ double wsum[4];
    const int lane = tid & 63, wave = tid >> 6;
    if (lane == 0) wsum[wave] = s;
    __syncthreads();
    if (tid == 0) {
        double total = wsum[0] + wsum[1] + wsum[2] + wsum[3];
        meanOut[0] = (float)(total / (double)NTOT);
    }
}

// ---------------------------------------------------------------------------
// K3: out[i] = mean + log(sigma[i]) + 0.5 + 0.5*log(2*pi)
// ---------------------------------------------------------------------------
__global__ __launch_bounds__(256) void out_kernel(
    const float* __restrict__ sigma, const float* __restrict__ meanPtr,
    float* __restrict__ out)
{
    const size_t v = (size_t)blockIdx.x * 256 + threadIdx.x;  // float4 index
    const float mean = *meanPtr;
    float4 s = ((const float4*)sigma)[v];
    float4 o;
    o.x = mean + __logf(s.x) + ENTC;
    o.y = mean + __logf(s.y) + ENTC;
    o.z = mean + __logf(s.z) + ENTC;
    o.w = mean + __logf(s.w) + ENTC;
    ((float4*)out)[v] = o;
}

// ---------------------------------------------------------------------------
extern "C" void kernel_launch(void* const* d_in, const int* in_sizes, int n_in,
                              void* d_out, int out_size, void* d_ws, size_t ws_size,
                              hipStream_t stream) {
    const float* rewards   = (const float*)d_in[0];   // [B,T]
    const float* critic    = (const float*)d_in[1];   // [B,T+1]
    const float* mu        = (const float*)d_in[2];   // [B,T,A]
    const float* sigma     = (const float*)d_in[3];
    const float* old_mu    = (const float*)d_in[4];
    const float* old_sigma = (const float*)d_in[5];
    const float* actions   = (const float*)d_in[6];
    const int*   dones     = (const int*)d_in[7];     // [B,T]
    float* out = (float*)d_out;

    char* ws = (char*)d_ws;
    float*  meanPtr  = (float*)ws;                    // 4 B
    double* partials = (double*)(ws + 256);           // 16 KB
    float*  adv      = (float*)(ws + 32768);          // 4 MB (B*T floats)

    gae_kernel<<<BB, 256, 0, stream>>>(rewards, critic, dones, adv);
    obj_kernel<<<NB2, 256, 0, stream>>>(mu, sigma, old_mu, old_sigma,
                                        actions, adv, partials);
    reduce_kernel<<<1, 256, 0, stream>>>(partials, meanPtr);
    out_kernel<<<(int)(NTOT / 4 / 256), 256, 0, stream>>>(sigma, meanPtr, out);
}